// Round 4
// baseline (9942.605 us; speedup 1.0000x reference)
//
#include <hip/hip_runtime.h>
#include <hip/hip_bf16.h>
#include <math.h>

#define BB 64
#define SS 512
#define EE 256
#define HH 512
#define GG 2048   // 4H
#define NWG 512
#define HSTRIDE 32768                       // floats per phase: 64 b * 512 k
#define DSTRIDE ((size_t)(SS+1)*HSTRIDE)    // floats per direction
#define SWZ(q) ((q) ^ (((q) >> 3) & 7))     // LDS quad swizzle (involution)

// global -> LDS direct copy, 16 B per lane; LDS dest = uniform base + lane*16,
// per-lane global source carries the swizzle (guide §5 / m173 pattern).
#define G2L(g, l) __builtin_amdgcn_global_load_lds(                       \
    (const __attribute__((address_space(1))) unsigned int*)(g),           \
    (__attribute__((address_space(3))) unsigned int*)(l), 16, 0, 0)

// ---------------------------------------------------------------------------
// K_pre: fold dense + CRF kernel:  wde[tag][k] = sum_m Wd[k][m]*crfW[m][tag]
// ---------------------------------------------------------------------------
__global__ void k_wde(const float* __restrict__ Wd, const float* __restrict__ bd,
                      const float* __restrict__ crfW, const float* __restrict__ crfb,
                      float* __restrict__ wde, float* __restrict__ bde)
{
  const int idx = blockIdx.x*256 + threadIdx.x;
  if (idx < 9*1024) {
    const int tag = idx >> 10, k = idx & 1023;
    float s = 0.f;
    #pragma unroll
    for (int m = 0; m < 9; ++m) s += Wd[k*9 + m] * crfW[m*9 + tag];
    wde[idx] = s;
  }
  if (idx < 9) {
    float s = crfb[idx];
    #pragma unroll
    for (int m = 0; m < 9; ++m) s += bd[m]*crfW[m*9 + idx];
    bde[idx] = s;
  }
}

// ---------------------------------------------------------------------------
// K2: persistent fused bidirectional LSTM.
// 512 WGs x 512 threads; k-split 64 (kcc = lane), 1 column per wave,
// 8 columns per WG. Per-thread registers: ureg[8]+wreg[4] = 48 + part[16][4]
// = 64 + temps ~= 125 <= 128, so the backend's favorite 128-VGPR bracket
// (chosen in R1/R2/R3 regardless of attributes) finally fits with NO spill.
// __launch_bounds__(512,4) pins VGPR<=128 -> 4 waves/SIMD -> 2 WGs/CU ->
// all 512 WGs resident (cooperative-safe; LDS ~50KB*2 <= 160KB).
// Staging uses global_load_lds width=16 (zero staging VGPRs, no ds_writes):
// LDS dest is linear (base + lane*16), the per-lane GLOBAL source address is
// pre-swizzled with SWZ (involution), so compute-side reads use the same SWZ.
// wg -> d = wg&1, bq = (wg>>1)&3, cg = wg>>3 (0..63). Group = 64 WGs sharing
// wg%8 (same XCD); 64 ready-flags polled by wave 0.
// Producer h stores: 8-B packed relaxed agent atomics, LDS-staged.
// h layout: h_all[d][phase 1..512][b][k]; phase-0 slot never touched.
// ---------------------------------------------------------------------------
__global__ __launch_bounds__(512, 4) void k_lstm(
    const int* __restrict__ inputs, const float* __restrict__ emb,
    const float* __restrict__ Uf, const float* __restrict__ Ub,
    const float* __restrict__ Wf, const float* __restrict__ Wb,
    const float* __restrict__ bf, const float* __restrict__ bb2,
    float* __restrict__ h_all, unsigned int* __restrict__ bars)
{
  const int wg = blockIdx.x;
  const int d  = wg & 1;
  const int bq = (wg >> 1) & 3;
  const int cg = wg >> 3;                    // 0..63
  const float* __restrict__ U    = d ? Ub  : Uf;
  const float* __restrict__ W    = d ? Wb  : Wf;
  const float* __restrict__ bias = d ? bb2 : bf;
  float* __restrict__ h_d = h_all + (size_t)d * DSTRIDE;
  unsigned int* __restrict__ rdy = bars + (wg & 7)*64;   // 64 flags / group

  __shared__ float xs[4096];     // [16 b][256 k] source-swizzled (16 KB)
  __shared__ float hs[8192];     // [16 b][512 k] source-swizzled (32 KB)
  __shared__ float hst[144];     // [16 b][8 col] stride 9 (out-stage)
  __shared__ int   tok_l[16];

  const int tid  = threadIdx.x;
  const int w    = tid >> 6;                 // 0..7 = column within WG
  const int lane = tid & 63;                 // = kcc (64-way k split)
  const int col  = cg*8 + w;                 // this thread's h-column
  const int swzl = SWZ(lane);                // hoisted source/read swizzle

  // weights in registers: k-split 64-way by lane (48 VGPRs total)
  float4 ureg[8];    // U[k = lane*8+i][gates ifgo at col]
  #pragma unroll
  for (int i = 0; i < 8; ++i) {
    const float* ur = U + (size_t)(lane*8 + i)*GG + col;
    ureg[i] = make_float4(ur[0], ur[512], ur[1024], ur[1536]);
  }
  float4 wreg[4];    // W[k = lane*4+i][gates at col]
  #pragma unroll
  for (int i = 0; i < 4; ++i) {
    const float* wr = W + (size_t)(lane*4 + i)*GG + col;
    wreg[i] = make_float4(wr[0], wr[512], wr[1024], wr[1536]);
  }
  const float4 breg = make_float4(bias[col], bias[512+col], bias[1024+col], bias[1536+col]);
  float cst = 0.f;                           // c-state for (b = bq*16 + (lane&15), col)

  #pragma unroll 1
  for (int p = 0; p < 512; ++p) {
    const int t = d ? (511 - p) : p;
    const float* __restrict__ hp = h_d + (size_t)p     * HSTRIDE;
    float* __restrict__ hn       = h_d + (size_t)(p+1) * HSTRIDE;

    if (tid < 16) tok_l[tid] = inputs[(bq*16 + tid)*SS + t];
    __syncthreads();                         // A: tok ready; xs/hs/hst free

    // async-stage x tile [16][256]: wave w stages rows w*2, w*2+1.
    // LDS slot (b, lane) receives emb quad SWZ(lane) -> read back with SWZ.
    #pragma unroll
    for (int c = 0; c < 2; ++c) {
      const int b = w*2 + c;
      G2L(&emb[(size_t)tok_l[b]*EE + swzl*4], &xs[b*256]);
    }

    // wave 0 polls this group's 64 producer flags (h(p) ready)
    if (p) {
      if (w == 0) {
        for (;;) {
          const unsigned int v =
            __hip_atomic_load(&rdy[lane], __ATOMIC_RELAXED, __HIP_MEMORY_SCOPE_AGENT);
          if (__all((int)(v >= (unsigned)p))) break;
          __builtin_amdgcn_s_sleep(1);
        }
      }
    }
    asm volatile("s_waitcnt vmcnt(0)" ::: "memory");   // xs landed (per wave)
    __syncthreads();                         // B: xs ready; h(p) visible

    // async-stage h tile [16][512]: wave w stages half-rows; latency hides
    // under x@W below. Slot (b, qk0+lane) <- h quad qk0+SWZ(lane).
    if (p) {
      #pragma unroll
      for (int c = 0; c < 4; ++c) {
        const int idx = w*4 + c, b = idx >> 1, qk0 = (idx & 1)*64;
        G2L(&hp[(size_t)(bq*16 + b)*HH + (qk0 + swzl)*4], &hs[b*512 + qk0*4]);
      }
    }

    float part[16][4];
    #pragma unroll
    for (int b = 0; b < 16; ++b) { part[b][0]=0.f; part[b][1]=0.f; part[b][2]=0.f; part[b][3]=0.f; }

    // x @ W  (K = 256, 4 k per thread = 1 quad: k = lane*4 .. lane*4+3)
    const float4 w0 = wreg[0], w1 = wreg[1], w2 = wreg[2], w3 = wreg[3];
    #pragma unroll
    for (int b = 0; b < 16; ++b) {
      const float4 hv = *(const float4*)&xs[b*256 + swzl*4];
      part[b][0] += hv.x*w0.x + hv.y*w1.x + hv.z*w2.x + hv.w*w3.x;
      part[b][1] += hv.x*w0.y + hv.y*w1.y + hv.z*w2.y + hv.w*w3.y;
      part[b][2] += hv.x*w0.z + hv.y*w1.z + hv.z*w2.z + hv.w*w3.z;
      part[b][3] += hv.x*w0.w + hv.y*w1.w + hv.z*w2.w + hv.w*w3.w;
    }

    if (p) {
      asm volatile("s_waitcnt vmcnt(0)" ::: "memory");  // hs landed (per wave)
      __syncthreads();                       // C: hs ready

      // h @ U  (K = 512, 8 k per thread = quads 2*lane, 2*lane+1)
      const int swz2a = SWZ(2*lane)*4, swz2b = SWZ(2*lane + 1)*4;
      #pragma unroll
      for (int b = 0; b < 16; ++b) {
        const float4 h0 = *(const float4*)&hs[b*512 + swz2a];
        const float4 h1 = *(const float4*)&hs[b*512 + swz2b];
        part[b][0] += h0.x*ureg[0].x + h0.y*ureg[1].x + h0.z*ureg[2].x + h0.w*ureg[3].x
                    + h1.x*ureg[4].x + h1.y*ureg[5].x + h1.z*ureg[6].x + h1.w*ureg[7].x;
        part[b][1] += h0.x*ureg[0].y + h0.y*ureg[1].y + h0.z*ureg[2].y + h0.w*ureg[3].y
                    + h1.x*ureg[4].y + h1.y*ureg[5].y + h1.z*ureg[6].y + h1.w*ureg[7].y;
        part[b][2] += h0.x*ureg[0].z + h0.y*ureg[1].z + h0.z*ureg[2].z + h0.w*ureg[3].z
                    + h1.x*ureg[4].z + h1.y*ureg[5].z + h1.z*ureg[6].z + h1.w*ureg[7].z;
        part[b][3] += h0.x*ureg[0].w + h0.y*ureg[1].w + h0.z*ureg[2].w + h0.w*ureg[3].w
                    + h1.x*ureg[4].w + h1.y*ureg[5].w + h1.z*ureg[6].w + h1.w*ureg[7].w;
      }
    }

    // reduce over 64 lanes: 4 keep/send levels distribute the 16 b-rows
    // (row = lane&15), then two symmetric levels (xor-16, xor-32) finish the
    // sum; lanes {L, L^16, L^32, L^48} end with identical full sums.
    const int b0 = lane & 1, b1 = (lane >> 1) & 1, b2 = (lane >> 2) & 1, b3 = (lane >> 3) & 1;
    float r1[8][4], r2[4][4], r3[2][4], r4[4], z[4];
    #pragma unroll
    for (int i = 0; i < 8; ++i)
      #pragma unroll
      for (int g = 0; g < 4; ++g) {
        const float keep = b0 ? part[2*i+1][g] : part[2*i][g];
        const float send = b0 ? part[2*i][g]   : part[2*i+1][g];
        r1[i][g] = keep + __shfl_xor(send, 1, 64);
      }
    #pragma unroll
    for (int i = 0; i < 4; ++i)
      #pragma unroll
      for (int g = 0; g < 4; ++g) {
        const float keep = b1 ? r1[2*i+1][g] : r1[2*i][g];
        const float send = b1 ? r1[2*i][g]   : r1[2*i+1][g];
        r2[i][g] = keep + __shfl_xor(send, 2, 64);
      }
    #pragma unroll
    for (int i = 0; i < 2; ++i)
      #pragma unroll
      for (int g = 0; g < 4; ++g) {
        const float keep = b2 ? r2[2*i+1][g] : r2[2*i][g];
        const float send = b2 ? r2[2*i][g]   : r2[2*i+1][g];
        r3[i][g] = keep + __shfl_xor(send, 4, 64);
      }
    #pragma unroll
    for (int g = 0; g < 4; ++g) {
      const float keep = b3 ? r3[1][g] : r3[0][g];
      const float send = b3 ? r3[0][g] : r3[1][g];
      r4[g] = keep + __shfl_xor(send, 8, 64);
    }
    #pragma unroll
    for (int g = 0; g < 4; ++g) {
      const float s16 = r4[g] + __shfl_xor(r4[g], 16, 64);
      z[g] = s16 + __shfl_xor(s16, 32, 64);
    }

    // gates (Keras order i,f,g,o) for (b = bq*16 + (lane&15), col)
    const float zi = z[0] + breg.x;
    const float zf = z[1] + breg.y;
    const float zg = z[2] + breg.z;
    const float zo = z[3] + breg.w;
    const float ig = 1.f/(1.f + expf(-zi));
    const float fg = 1.f/(1.f + expf(-zf));
    const float tg = tanhf(zg);
    const float og = 1.f/(1.f + expf(-zo));
    cst = fg*cst + ig*tg;
    const float hval = og * tanhf(cst);

    // stage output tile in LDS (one writer per cell: lane<16 per wave)
    if (lane < 16) hst[lane*9 + w] = hval;
    __syncthreads();                         // D: hst ready
    if (tid < 64) {
      const int b = tid >> 2, cp = tid & 3;  // 8-B packed spans per b-row
      union { float f[2]; unsigned long long u; } v;
      v.f[0] = hst[b*9 + cp*2];
      v.f[1] = hst[b*9 + cp*2 + 1];
      __hip_atomic_store((unsigned long long*)&hn[(size_t)(bq*16 + b)*HH + cg*8 + cp*2],
                         v.u, __ATOMIC_RELAXED, __HIP_MEMORY_SCOPE_AGENT);
    }

    // drain stores, then publish readiness (single flag store, no RMW)
    asm volatile("s_waitcnt vmcnt(0)" ::: "memory");
    __syncthreads();                         // E
    if (tid == 0)
      __hip_atomic_store(&rdy[cg], (unsigned)(p+1), __ATOMIC_RELAXED, __HIP_MEMORY_SCOPE_AGENT);
  }
}

// ---------------------------------------------------------------------------
// K3: pots[b][t][tag] = [h_fw(t), h_bw(t)] @ wde^T + bde (+ boundaries)
// h layout: [d][phase][b][k]
// ---------------------------------------------------------------------------
__global__ __launch_bounds__(256) void k_dense(
    const float* __restrict__ h_all, const float* __restrict__ wde,
    const float* __restrict__ bde, const float* __restrict__ lb,
    const float* __restrict__ rb, float* __restrict__ pots)
{
  const int wv   = threadIdx.x >> 6;
  const int lane = threadIdx.x & 63;
  const int tok  = blockIdx.x*4 + wv;          // 0..32767
  const int b = tok >> 9, t = tok & 511;
  const float* hf = h_all + (size_t)(t+1)*HSTRIDE + (size_t)b*HH;
  const float* hb = h_all + DSTRIDE + (size_t)(SS-t)*HSTRIDE + (size_t)b*HH;
  float hr[16];
  *(float4*)&hr[0]  = *(const float4*)&hf[lane*8];
  *(float4*)&hr[4]  = *(const float4*)&hf[lane*8+4];
  *(float4*)&hr[8]  = *(const float4*)&hb[lane*8];
  *(float4*)&hr[12] = *(const float4*)&hb[lane*8+4];
  float s[9];
  #pragma unroll
  for (int tg = 0; tg < 9; ++tg) {
    const float* w0 = wde + tg*1024 + lane*8;
    const float* w1 = w0 + 512;
    const float4 a0 = *(const float4*)w0, a1 = *(const float4*)(w0+4);
    const float4 b0 = *(const float4*)w1, b1 = *(const float4*)(w1+4);
    s[tg] = hr[0]*a0.x + hr[1]*a0.y + hr[2]*a0.z + hr[3]*a0.w
          + hr[4]*a1.x + hr[5]*a1.y + hr[6]*a1.z + hr[7]*a1.w
          + hr[8]*b0.x + hr[9]*b0.y + hr[10]*b0.z + hr[11]*b0.w
          + hr[12]*b1.x + hr[13]*b1.y + hr[14]*b1.z + hr[15]*b1.w;
  }
  #pragma unroll
  for (int tg = 0; tg < 9; ++tg) {
    #pragma unroll
    for (int off = 32; off > 0; off >>= 1) s[tg] += __shfl_xor(s[tg], off, 64);
  }
  if (lane < 9) {
    float v = s[lane] + bde[lane];
    if (t == 0)   v += lb[lane];
    if (t == 511) v += rb[lane];
    pots[(size_t)tok*9 + lane] = v;
  }
}

// ---------------------------------------------------------------------------
// K4: Viterbi decode. One wave per batch row. pots row staged in LDS once
// (coalesced float4) instead of 512 serial 36-B global reads.
// ---------------------------------------------------------------------------
__global__ __launch_bounds__(64) void k_viterbi(
    const float* __restrict__ pots, const float* __restrict__ trans,
    float* __restrict__ dec)
{
  const int b = blockIdx.x;
  const int lane = threadIdx.x;
  __shared__ float pl[4608];
  __shared__ unsigned char bp[511*9];
  __shared__ unsigned char tl[512];
  __shared__ float af[9];
  const float* pb = pots + (size_t)b*512*9;
  for (int i = lane; i < 1152; i += 64)
    *(float4*)&pl[i*4] = *(const float4*)&pb[i*4];
  float tr[9];
  #pragma unroll
  for (int i = 0; i < 9; ++i) tr[i] = (lane < 9) ? trans[i*9 + lane] : 0.f;
  __syncthreads();
  float alpha = (lane < 9) ? pl[lane] : -3e38f;
  for (int t = 1; t < 512; ++t) {
    float best = -3e38f; int bi = 0;
    #pragma unroll
    for (int i = 0; i < 9; ++i) {
      const float sc = __shfl(alpha, i, 64) + tr[i];
      if (sc > best) { best = sc; bi = i; }     // strict > keeps first max (jnp.argmax)
    }
    if (lane < 9) {
      bp[(t-1)*9 + lane] = (unsigned char)bi;
      alpha = best + pl[t*9 + lane];
    }
  }
  if (lane < 9) af[lane] = alpha;
  __syncthreads();
  if (lane == 0) {
    int tg = 0; float bv = af[0];
    #pragma unroll
    for (int i = 1; i < 9; ++i) if (af[i] > bv) { bv = af[i]; tg = i; }
    tl[511] = (unsigned char)tg;
    for (int t = 510; t >= 0; --t) { tg = bp[t*9 + tg]; tl[t] = (unsigned char)tg; }
  }
  __syncthreads();
  for (int t = lane; t < 512; t += 64) dec[(size_t)b*512 + t] = (float)tl[t];
}

// ---------------------------------------------------------------------------
extern "C" void kernel_launch(void* const* d_in, const int* in_sizes, int n_in,
                              void* d_out, int out_size, void* d_ws, size_t ws_size,
                              hipStream_t stream)
{
  const int*   inputs = (const int*)  d_in[0];
  const float* emb    = (const float*)d_in[1];
  const float* Wf     = (const float*)d_in[2];
  const float* Uf     = (const float*)d_in[3];
  const float* bf     = (const float*)d_in[4];
  const float* Wb     = (const float*)d_in[5];
  const float* Ub     = (const float*)d_in[6];
  const float* bb2    = (const float*)d_in[7];
  const float* Wd     = (const float*)d_in[8];
  const float* bd     = (const float*)d_in[9];
  const float* crfW   = (const float*)d_in[10];
  const float* crfb   = (const float*)d_in[11];
  const float* trans  = (const float*)d_in[12];
  const float* lb     = (const float*)d_in[13];
  const float* rb     = (const float*)d_in[14];

  float* ws   = (float*)d_ws;
  unsigned int* bars = (unsigned int*)d_ws;           // first 16 KB: ready flags
  float* hall = ws + 4096;                            // 2*513*32768 floats (~134.5 MB)
  float* wde  = hall + 2*DSTRIDE;                     // 9216 floats
  float* bde  = wde + 9216;                           // 16 floats

  float* dec  = (float*)d_out;                        // 32768 floats
  float* pots = dec + (size_t)BB*SS;                  // 294912 floats

  hipMemsetAsync(d_ws, 0, 16384, stream);

  k_wde<<<36, 256, 0, stream>>>(Wd, bd, crfW, crfb, wde, bde);

  {
    const int*   a0 = inputs; const float* a1 = emb;
    const float* a2 = Uf;  const float* a3 = Ub;
    const float* a4 = Wf;  const float* a5 = Wb;
    const float* a6 = bf;  const float* a7 = bb2;
    float* a8 = hall; unsigned int* a9 = bars;
    void* args[] = { &a0,&a1,&a2,&a3,&a4,&a5,&a6,&a7,&a8,&a9 };
    if (hipLaunchCooperativeKernel((void*)k_lstm, dim3(NWG), dim3(512),
                                   args, 0, stream) != hipSuccess) {
      k_lstm<<<NWG, 512, 0, stream>>>(inputs, emb, Uf, Ub, Wf, Wb, bf, bb2, hall, bars);
    }
  }

  k_dense<<<8192, 256, 0, stream>>>(hall, wde, bde, lb, rb, pots);
  k_viterbi<<<64, 64, 0, stream>>>(pots, trans, dec);
}

// Round 7
// 6349.616 us; speedup vs baseline: 1.5659x; 1.5659x over previous
//
#include <hip/hip_runtime.h>
#include <hip/hip_bf16.h>
#include <math.h>

#define BB 64
#define SS 512
#define EE 256
#define HH 512
#define GG 2048   // 4H
#define HSTRIDE 32768                       // floats per phase: 64 b * 512 k
#define DSTRIDE ((size_t)(SS+1)*HSTRIDE)    // floats per direction
#define SWZ(q) ((q) ^ (((q) >> 3) & 7))     // LDS quad swizzle (involution)

// global -> LDS direct copy, 16 B per lane; LDS dest = wave-uniform base +
// lane*16, per-lane GLOBAL source carries the swizzle. Proven correct in R4.
#define G2L(g, l) __builtin_amdgcn_global_load_lds(                       \
    (const __attribute__((address_space(1))) unsigned int*)(g),           \
    (__attribute__((address_space(3))) unsigned int*)(l), 16, 0, 0)

// ---------------------------------------------------------------------------
// K_pre: fold dense + CRF kernel:  wde[tag][k] = sum_m Wd[k][m]*crfW[m][tag]
// ---------------------------------------------------------------------------
__global__ void k_wde(const float* __restrict__ Wd, const float* __restrict__ bd,
                      const float* __restrict__ crfW, const float* __restrict__ crfb,
                      float* __restrict__ wde, float* __restrict__ bde)
{
  const int idx = blockIdx.x*256 + threadIdx.x;
  if (idx < 9*1024) {
    const int tag = idx >> 10, k = idx & 1023;
    float s = 0.f;
    #pragma unroll
    for (int m = 0; m < 9; ++m) s += Wd[k*9 + m] * crfW[m*9 + tag];
    wde[idx] = s;
  }
  if (idx < 9) {
    float s = crfb[idx];
    #pragma unroll
    for (int m = 0; m < 9; ++m) s += bd[m]*crfW[m*9 + idx];
    bde[idx] = s;
  }
}

// ---------------------------------------------------------------------------
// K2: persistent fused bidirectional LSTM — R0's proven structure (256 WGs x
// 256 threads, launch_bounds(256,1), 256-VGPR no-spill shape) with exactly
// two proven deltas:
//  (1) x-staging is now an async global_load_lds PREFETCH one step ahead
//      (double-buffered xs[2], tok_l[2]; pre-swizzled source, linear LDS
//      dest — R4-proven). Removes the emb-gather latency from the serial
//      recurrence chain at zero VGPR cost. Completion of step p+1's staging
//      is enforced by step p's existing vmcnt(0) drain + barriers.
//  (2) h-stores are 8-B packed relaxed agent atomics (R2/R3-proven; halves
//      the write-through transactions the drain waits on).
// Everything else (groups, flags, poll, barriers, reduce tree, gate math,
// launch ladder) is byte-identical to R0.
// wg -> d = wg&1, bq = (wg>>1)&3, cg = wg>>3 (0..31). Group = 32 WGs
// sharing wg%8 -> same XCD; 32 ready-flags polled by wave 0.
// h layout: h_all[d][phase 1..512][b][k]; phase-0 slot never touched.
// ---------------------------------------------------------------------------
__global__ __launch_bounds__(256, 1) void k_lstm(
    const int* __restrict__ inputs, const float* __restrict__ emb,
    const float* __restrict__ Uf, const float* __restrict__ Ub,
    const float* __restrict__ Wf, const float* __restrict__ Wb,
    const float* __restrict__ bf, const float* __restrict__ bb2,
    float* __restrict__ h_all, unsigned int* __restrict__ bars)
{
  const int wg = blockIdx.x;
  const int d  = wg & 1;
  const int bq = (wg >> 1) & 3;
  const int cg = wg >> 3;                    // 0..31
  const float* __restrict__ U    = d ? Ub  : Uf;
  const float* __restrict__ W    = d ? Wb  : Wf;
  const float* __restrict__ bias = d ? bb2 : bf;
  float* __restrict__ h_d = h_all + (size_t)d * DSTRIDE;
  unsigned int* __restrict__ rdy = bars + (wg & 7)*64;   // 32 flags / group

  __shared__ float xs[2][4096];  // [buf][16 b][256 k] quad-swizzled (32 KB)
  __shared__ float hs[8192];     // [16 b][512 k] quad-swizzled (32 KB)
  __shared__ float hst[272];     // [16 b][16 col] stride 17 (out-stage)
  __shared__ int   tok_l[2][16];

  const int tid  = threadIdx.x;
  const int w    = tid >> 6;
  const int lane = tid & 63;
  const int kcc  = lane & 15;
  const int jj   = lane >> 4;
  const int col  = cg*16 + w*4 + jj;         // this thread's h-column
  const int swzl = SWZ(lane);                // hoisted source swizzle

  // weights in registers: k-split 16-way by kcc (identical to R0)
  float4 ureg[32];   // U[k = kcc*32+i][gates ifgo at col]
  #pragma unroll
  for (int i = 0; i < 32; ++i) {
    const float* ur = U + (size_t)(kcc*32 + i)*GG + col;
    ureg[i] = make_float4(ur[0], ur[512], ur[1024], ur[1536]);
  }
  float4 wreg[16];   // W[k = kcc*16+i][gates at col]
  #pragma unroll
  for (int i = 0; i < 16; ++i) {
    const float* wr = W + (size_t)(kcc*16 + i)*GG + col;
    wreg[i] = make_float4(wr[0], wr[512], wr[1024], wr[1536]);
  }
  const float4 breg = make_float4(bias[col], bias[512+col], bias[1024+col], bias[1536+col]);
  float cst = 0.f;                           // c-state for (b = bq*16+kcc, col)

  // prologue: stage xs[0] for p=0 (async copy, then drain)
  if (tid < 16) tok_l[0][tid] = inputs[(bq*16 + tid)*SS + (d ? 511 : 0)];
  __syncthreads();
  #pragma unroll
  for (int r = 0; r < 4; ++r) {
    const int b = r*4 + w;                   // wave w stages rows w, 4+w, 8+w, 12+w
    G2L(&emb[(size_t)tok_l[0][b]*EE + swzl*4], &xs[0][b*256]);
  }
  asm volatile("s_waitcnt vmcnt(0)" ::: "memory");
  __syncthreads();                           // xs[0] ready

  #pragma unroll 1
  for (int p = 0; p < 512; ++p) {
    const int cur = p & 1, nxt = cur ^ 1;
    const float* __restrict__ hp = h_d + (size_t)p     * HSTRIDE;
    float* __restrict__ hn       = h_d + (size_t)(p+1) * HSTRIDE;
    const float* __restrict__ xsc = xs[cur];

    // tokens for step p+1 into the other buffer
    if (p+1 < 512 && tid < 16) {
      const int t1 = d ? (511 - (p+1)) : (p+1);
      tok_l[nxt][tid] = inputs[(bq*16 + tid)*SS + t1];
    }
    __syncthreads();                         // A: tok_l[nxt] ready; hst/xs[nxt] free

    // async x-prefetch for step p+1 (zero VGPR; completes under this step's
    // compute; drained by this step's tail vmcnt(0) + barriers)
    if (p+1 < 512) {
      #pragma unroll
      for (int r = 0; r < 4; ++r) {
        const int b = r*4 + w;
        G2L(&emb[(size_t)tok_l[nxt][b]*EE + swzl*4], &xs[nxt][b*256]);
      }
    }

    // wave 0 polls this group's 32 producer flags (h(p) ready)
    if (p) {
      if (w == 0) {
        for (;;) {
          unsigned int v = 0xFFFFFFFFu;
          if (lane < 32)
            v = __hip_atomic_load(&rdy[lane], __ATOMIC_RELAXED, __HIP_MEMORY_SCOPE_AGENT);
          if (__all((int)(v >= (unsigned)p))) break;
          __builtin_amdgcn_s_sleep(1);
        }
      }
      __syncthreads();                       // B: h(p) visible; orders loads below
    }

    // issue h(p) plain coalesced loads (latency hidden by x@W below)
    float4 hld4[8];
    if (p) {
      #pragma unroll
      for (int r = 0; r < 8; ++r) {
        const int q = r*256 + tid, b = q >> 7, qh = q & 127;
        hld4[r] = *(const float4*)&hp[(size_t)(bq*16 + b)*HH + qh*4];
      }
    }

    float part[16][4];
    #pragma unroll
    for (int b = 0; b < 16; ++b) { part[b][0]=0.f; part[b][1]=0.f; part[b][2]=0.f; part[b][3]=0.f; }

    // x @ W  (K = 256, 16 k per thread, 16 b rows)
    #pragma unroll
    for (int b = 0; b < 16; ++b) {
      const float* xrow = &xsc[b*256];
      #pragma unroll
      for (int i = 0; i < 4; ++i) {
        const int q = kcc*4 + i;
        const float4 hv = *(const float4*)&xrow[SWZ(q)*4];
        const float4 w0 = wreg[i*4+0], w1 = wreg[i*4+1], w2 = wreg[i*4+2], w3 = wreg[i*4+3];
        part[b][0] += hv.x*w0.x + hv.y*w1.x + hv.z*w2.x + hv.w*w3.x;
        part[b][1] += hv.x*w0.y + hv.y*w1.y + hv.z*w2.y + hv.w*w3.y;
        part[b][2] += hv.x*w0.z + hv.y*w1.z + hv.z*w2.z + hv.w*w3.z;
        part[b][3] += hv.x*w0.w + hv.y*w1.w + hv.z*w2.w + hv.w*w3.w;
      }
    }

    if (p) {
      // park h(p) into LDS (vmcnt wait on hld4 auto-inserted here)
      #pragma unroll
      for (int r = 0; r < 8; ++r) {
        const int q = r*256 + tid, b = q >> 7, qh = q & 127;
        *(float4*)&hs[b*512 + SWZ(qh)*4] = hld4[r];
      }
      __syncthreads();                       // C: hs ready

      // h @ U  (K = 512, 32 k per thread, 16 b rows)
      #pragma unroll
      for (int b = 0; b < 16; ++b) {
        const float* hrow = &hs[b*512];
        #pragma unroll
        for (int i = 0; i < 8; ++i) {
          const int q = kcc*8 + i;
          const float4 hv = *(const float4*)&hrow[SWZ(q)*4];
          const float4 u0 = ureg[i*4+0], u1 = ureg[i*4+1], u2 = ureg[i*4+2], u3 = ureg[i*4+3];
          part[b][0] += hv.x*u0.x + hv.y*u1.x + hv.z*u2.x + hv.w*u3.x;
          part[b][1] += hv.x*u0.y + hv.y*u1.y + hv.z*u2.y + hv.w*u3.y;
          part[b][2] += hv.x*u0.z + hv.y*u1.z + hv.z*u2.z + hv.w*u3.z;
          part[b][3] += hv.x*u0.w + hv.y*u1.w + hv.z*u2.w + hv.w*u3.w;
        }
      }
    }

    // shuffle-tree reduce over 16 kcc lanes; lane ends with b = kcc (R0 tree)
    const int b0 = lane & 1, b1 = (lane >> 1) & 1, b2 = (lane >> 2) & 1, b3 = (lane >> 3) & 1;
    float r1[8][4], r2[4][4], r3[2][4], z[4];
    #pragma unroll
    for (int i = 0; i < 8; ++i)
      #pragma unroll
      for (int g = 0; g < 4; ++g) {
        const float keep = b0 ? part[2*i+1][g] : part[2*i][g];
        const float send = b0 ? part[2*i][g]   : part[2*i+1][g];
        r1[i][g] = keep + __shfl_xor(send, 1, 64);
      }
    #pragma unroll
    for (int i = 0; i < 4; ++i)
      #pragma unroll
      for (int g = 0; g < 4; ++g) {
        const float keep = b1 ? r1[2*i+1][g] : r1[2*i][g];
        const float send = b1 ? r1[2*i][g]   : r1[2*i+1][g];
        r2[i][g] = keep + __shfl_xor(send, 2, 64);
      }
    #pragma unroll
    for (int i = 0; i < 2; ++i)
      #pragma unroll
      for (int g = 0; g < 4; ++g) {
        const float keep = b2 ? r2[2*i+1][g] : r2[2*i][g];
        const float send = b2 ? r2[2*i][g]   : r2[2*i+1][g];
        r3[i][g] = keep + __shfl_xor(send, 4, 64);
      }
    #pragma unroll
    for (int g = 0; g < 4; ++g) {
      const float keep = b3 ? r3[1][g] : r3[0][g];
      const float send = b3 ? r3[0][g] : r3[1][g];
      z[g] = keep + __shfl_xor(send, 8, 64);
    }

    // gates (Keras order i,f,g,o) for (b = bq*16+kcc, col)
    const float zi = z[0] + breg.x;
    const float zf = z[1] + breg.y;
    const float zg = z[2] + breg.z;
    const float zo = z[3] + breg.w;
    const float ig = 1.f/(1.f + expf(-zi));
    const float fg = 1.f/(1.f + expf(-zf));
    const float tg = tanhf(zg);
    const float og = 1.f/(1.f + expf(-zo));
    cst = fg*cst + ig*tg;
    const float hval = og * tanhf(cst);

    // stage output tile in LDS, then 8-B packed coalesced agent stores (R2)
    hst[kcc*17 + w*4 + jj] = hval;
    __syncthreads();                         // D: hst ready
    if (tid < 128) {
      const int b = tid >> 3, cp = tid & 7;  // 8-B packed spans per b-row
      union { float f[2]; unsigned long long u; } v;
      v.f[0] = hst[b*17 + cp*2];
      v.f[1] = hst[b*17 + cp*2 + 1];
      __hip_atomic_store((unsigned long long*)&hn[(size_t)(bq*16 + b)*HH + cg*16 + cp*2],
                         v.u, __ATOMIC_RELAXED, __HIP_MEMORY_SCOPE_AGENT);
    }

    // drain stores (also drains the x-prefetch, long since landed), publish
    asm volatile("s_waitcnt vmcnt(0)" ::: "memory");
    __syncthreads();                         // E
    if (tid == 0)
      __hip_atomic_store(&rdy[cg], (unsigned)(p+1), __ATOMIC_RELAXED, __HIP_MEMORY_SCOPE_AGENT);
  }
}

// ---------------------------------------------------------------------------
// K3: pots[b][t][tag] = [h_fw(t), h_bw(t)] @ wde^T + bde (+ boundaries)
// h layout: [d][phase][b][k]
// ---------------------------------------------------------------------------
__global__ __launch_bounds__(256) void k_dense(
    const float* __restrict__ h_all, const float* __restrict__ wde,
    const float* __restrict__ bde, const float* __restrict__ lb,
    const float* __restrict__ rb, float* __restrict__ pots)
{
  const int wv   = threadIdx.x >> 6;
  const int lane = threadIdx.x & 63;
  const int tok  = blockIdx.x*4 + wv;          // 0..32767
  const int b = tok >> 9, t = tok & 511;
  const float* hf = h_all + (size_t)(t+1)*HSTRIDE + (size_t)b*HH;
  const float* hb = h_all + DSTRIDE + (size_t)(SS-t)*HSTRIDE + (size_t)b*HH;
  float hr[16];
  *(float4*)&hr[0]  = *(const float4*)&hf[lane*8];
  *(float4*)&hr[4]  = *(const float4*)&hf[lane*8+4];
  *(float4*)&hr[8]  = *(const float4*)&hb[lane*8];
  *(float4*)&hr[12] = *(const float4*)&hb[lane*8+4];
  float s[9];
  #pragma unroll
  for (int tg = 0; tg < 9; ++tg) {
    const float* w0 = wde + tg*1024 + lane*8;
    const float* w1 = w0 + 512;
    const float4 a0 = *(const float4*)w0, a1 = *(const float4*)(w0+4);
    const float4 b0 = *(const float4*)w1, b1 = *(const float4*)(w1+4);
    s[tg] = hr[0]*a0.x + hr[1]*a0.y + hr[2]*a0.z + hr[3]*a0.w
          + hr[4]*a1.x + hr[5]*a1.y + hr[6]*a1.z + hr[7]*a1.w
          + hr[8]*b0.x + hr[9]*b0.y + hr[10]*b0.z + hr[11]*b0.w
          + hr[12]*b1.x + hr[13]*b1.y + hr[14]*b1.z + hr[15]*b1.w;
  }
  #pragma unroll
  for (int tg = 0; tg < 9; ++tg) {
    #pragma unroll
    for (int off = 32; off > 0; off >>= 1) s[tg] += __shfl_xor(s[tg], off, 64);
  }
  if (lane < 9) {
    float v = s[lane] + bde[lane];
    if (t == 0)   v += lb[lane];
    if (t == 511) v += rb[lane];
    pots[(size_t)tok*9 + lane] = v;
  }
}

// ---------------------------------------------------------------------------
// K4: Viterbi decode. One wave per batch row; pots row staged in LDS.
// ---------------------------------------------------------------------------
__global__ __launch_bounds__(64) void k_viterbi(
    const float* __restrict__ pots, const float* __restrict__ trans,
    float* __restrict__ dec)
{
  const int b = blockIdx.x;
  const int lane = threadIdx.x;
  __shared__ float pl[4608];
  __shared__ unsigned char bp[511*9];
  __shared__ unsigned char tl[512];
  __shared__ float af[9];
  const float* pb = pots + (size_t)b*512*9;
  for (int i = lane; i < 1152; i += 64)
    *(float4*)&pl[i*4] = *(const float4*)&pb[i*4];
  float tr[9];
  #pragma unroll
  for (int i = 0; i < 9; ++i) tr[i] = (lane < 9) ? trans[i*9 + lane] : 0.f;
  __syncthreads();
  float alpha = (lane < 9) ? pl[lane] : -3e38f;
  for (int t = 1; t < 512; ++t) {
    float best = -3e38f; int bi = 0;
    #pragma unroll
    for (int i = 0; i < 9; ++i) {
      const float sc = __shfl(alpha, i, 64) + tr[i];
      if (sc > best) { best = sc; bi = i; }     // strict > keeps first max (jnp.argmax)
    }
    if (lane < 9) {
      bp[(t-1)*9 + lane] = (unsigned char)bi;
      alpha = best + pl[t*9 + lane];
    }
  }
  if (lane < 9) af[lane] = alpha;
  __syncthreads();
  if (lane == 0) {
    int tg = 0; float bv = af[0];
    #pragma unroll
    for (int i = 1; i < 9; ++i) if (af[i] > bv) { bv = af[i]; tg = i; }
    tl[511] = (unsigned char)tg;
    for (int t = 510; t >= 0; --t) { tg = bp[t*9 + tg]; tl[t] = (unsigned char)tg; }
  }
  __syncthreads();
  for (int t = lane; t < 512; t += 64) dec[(size_t)b*512 + t] = (float)tl[t];
}

// ---------------------------------------------------------------------------
extern "C" void kernel_launch(void* const* d_in, const int* in_sizes, int n_in,
                              void* d_out, int out_size, void* d_ws, size_t ws_size,
                              hipStream_t stream)
{
  const int*   inputs = (const int*)  d_in[0];
  const float* emb    = (const float*)d_in[1];
  const float* Wf     = (const float*)d_in[2];
  const float* Uf     = (const float*)d_in[3];
  const float* bf     = (const float*)d_in[4];
  const float* Wb     = (const float*)d_in[5];
  const float* Ub     = (const float*)d_in[6];
  const float* bb2    = (const float*)d_in[7];
  const float* Wd     = (const float*)d_in[8];
  const float* bd     = (const float*)d_in[9];
  const float* crfW   = (const float*)d_in[10];
  const float* crfb   = (const float*)d_in[11];
  const float* trans  = (const float*)d_in[12];
  const float* lb     = (const float*)d_in[13];
  const float* rb     = (const float*)d_in[14];

  float* ws   = (float*)d_ws;
  unsigned int* bars = (unsigned int*)d_ws;           // first 16 KB: ready flags
  float* hall = ws + 4096;                            // 2*513*32768 floats (~134.5 MB)
  float* wde  = hall + 2*DSTRIDE;                     // 9216 floats
  float* bde  = wde + 9216;                           // 16 floats

  float* dec  = (float*)d_out;                        // 32768 floats
  float* pots = dec + (size_t)BB*SS;                  // 294912 floats

  hipMemsetAsync(d_ws, 0, 16384, stream);

  k_wde<<<36, 256, 0, stream>>>(Wd, bd, crfW, crfb, wde, bde);

  {
    const int*   a0 = inputs; const float* a1 = emb;
    const float* a2 = Uf;  const float* a3 = Ub;
    const float* a4 = Wf;  const float* a5 = Wb;
    const float* a6 = bf;  const float* a7 = bb2;
    float* a8 = hall; unsigned int* a9 = bars;
    void* args[] = { &a0,&a1,&a2,&a3,&a4,&a5,&a6,&a7,&a8,&a9 };
    // R0's exact launch ladder: coop 256 WGs, plain 256-WG fallback (256 WGs
    // are always co-resident — cannot hang either way).
    if (hipLaunchCooperativeKernel((void*)k_lstm, dim3(256), dim3(256),
                                   args, 0, stream) != hipSuccess) {
      k_lstm<<<256, 256, 0, stream>>>(inputs, emb, Uf, Ub, Wf, Wb, bf, bb2, hall, bars);
    }
  }

  k_dense<<<8192, 256, 0, stream>>>(hall, wde, bde, lb, rb, pots);
  k_viterbi<<<64, 64, 0, stream>>>(pots, trans, dec);
}